// Round 1
// baseline (224.340 us; speedup 1.0000x reference)
//
#include <hip/hip_runtime.h>

// PerturbedTopK: x(32,2048) f32, noise(32,500,2048) f32.
// out = [indicators (32,128,2048) f32, idx (32,500,128) as f32], concatenated.
//
// R9: occupancy round. ptk_select previously carried the rare fallback path
// (keys[32]) in-kernel, pushing VGPR into the 65..128 bin -> 4 waves/SIMD ->
// latency-bound (~2 TB/s effective). Now:
//  - fallback rows (C outside [128,256]) are deferred to a tiny ptk_fb kernel
//    via a ws list (counter zeroed in ptk_cutoff);
//  - __launch_bounds__(256, 8) forces <=64 VGPR -> 8 waves/SIMD;
//  - compaction is a static unrolled loop (no runtime-indexed p[] -> no
//    scratch risk);
//  - radix/emission templated on slot count (2/3/4 by C; E[C]~160 -> 3);
//  - cutoff radix truncated to bits 31..14 (floor class keeps count>=160,
//    tie class adds O(1) candidates vs 96 slack).

constexpr int B_     = 32;
constexpr int D_     = 2048;
constexpr int NS_    = 500;
constexpr int TOPK_  = 128;
constexpr int SLACK_ = 32;               // cutoff rank = 160
constexpr float SIGMA_  = 0.05f;
constexpr int PER_LANE_ = D_ / 64;       // 32 (fallback/cutoff)
constexpr int HALF_  = D_ / 2;           // 1024
constexpr int HPL_   = HALF_ / 64;       // 16 elements per lane per half-row
constexpr int CAP_   = 256;              // fast-path candidate cap (4 slots)
constexpr int JCHUNK_ = 8;               // ranks per hist block
constexpr int CUTBIT_END_ = 14;          // cutoff radix stops here (18 bits)

__device__ __forceinline__ uint32_t order_key(float f) {
  uint32_t u = __float_as_uint(f);
  return (u & 0x80000000u) ? ~u : (u | 0x80000000u);
}
__device__ __forceinline__ float inv_key(uint32_t k) {
  uint32_t u = (k & 0x80000000u) ? (k & 0x7FFFFFFFu) : ~k;
  return __uint_as_float(u);
}

// ---- kernel 1: per-b cutoff ~ (TOPK_+SLACK_)th largest of x_b (18-bit) ----
__global__ __launch_bounds__(64) void ptk_cutoff(const float* __restrict__ x,
                                                 float* __restrict__ cutf,
                                                 int* __restrict__ fb_cnt) {
  if (blockIdx.x == 0 && threadIdx.x == 0) fb_cnt[0] = 0;
  const int lane = threadIdx.x & 63;
  const int b = blockIdx.x;
  const float* __restrict__ xr = x + (size_t)b * D_;
  uint32_t keys[PER_LANE_];
#pragma unroll
  for (int j = 0; j < PER_LANE_; j += 4) {
    const float4 xv = *reinterpret_cast<const float4*>(xr + lane * PER_LANE_ + j);
    keys[j + 0] = order_key(xv.x); keys[j + 1] = order_key(xv.y);
    keys[j + 2] = order_key(xv.z); keys[j + 3] = order_key(xv.w);
  }
  uint32_t prefix = 0; int k = TOPK_ + SLACK_;
#pragma unroll 1
  for (int bit = 31; bit >= CUTBIT_END_; --bit) {
    const uint32_t want = (prefix >> bit) | 1u;
    int c = 0;
#pragma unroll
    for (int j = 0; j < PER_LANE_; ++j) c += ((keys[j] >> bit) == want) ? 1 : 0;
#pragma unroll
    for (int off = 32; off >= 1; off >>= 1) c += __shfl_xor(c, off);
    if (c >= k) prefix |= (1u << bit); else k -= c;
  }
  // prefix has zeros below CUTBIT_END_: floor of the rank-160 key's 18-bit
  // class -> count(x >= cf) >= 160, plus O(1) same-class ties (slack 96).
  if (lane == 0) cutf[b] = inv_key(prefix);
}

// ---- radix select + emission over NSLOT compacted 64-lane slots ----
template <int NSLOT>
__device__ __forceinline__ void finish_row(const uint2* __restrict__ comp,
                                           const int C0, const int C,
                                           float* __restrict__ idx_row,
                                           const int lane, const uint64_t below) {
  uint32_t kk[NSLOT], ki[NSLOT];
#pragma unroll
  for (int s = 0; s < NSLOT; ++s) {
    const int q = (s << 6) + lane;
    const int a = (q < C0) ? q : (CAP_ + q - C0);
    const uint2 v = (q < C) ? comp[a] : make_uint2(0u, 0u);
    kk[s] = v.x; ki[s] = v.y;   // pad key 0 never matches a radix class
  }

  // common-prefix skip: and/or reduce over candidate keys
  uint32_t orv = 0u, andv = 0xFFFFFFFFu;
#pragma unroll
  for (int s = 0; s < NSLOT; ++s) {
    const bool valid = ((s << 6) + lane) < C;
    orv  |= valid ? kk[s] : 0u;
    andv &= valid ? kk[s] : 0xFFFFFFFFu;
  }
#pragma unroll
  for (int off = 32; off >= 1; off >>= 1) {
    orv  |= __shfl_xor(orv, off);
    andv &= __shfl_xor(andv, off);
  }
  const uint32_t diff = orv ^ andv;

  uint32_t prefix; int r;
  if (diff == 0u) {
    prefix = orv; r = TOPK_;
  } else {
    const int startbit = 31 - __clz(diff);
    prefix = (startbit == 31) ? 0u : (andv & (0xFFFFFFFFu << (startbit + 1)));
    int k = TOPK_;
    int A = C;
#pragma unroll 1
    for (int bit = startbit; bit >= 0; --bit) {
      const uint32_t want = (prefix >> bit) | 1u;
      int c = 0;
#pragma unroll
      for (int s = 0; s < NSLOT; ++s)
        c += __popcll(__ballot((kk[s] >> bit) == want));
      if (c >= k) { prefix |= (1u << bit); A = c; }
      else        { k -= c; A -= c; }
      if (A == 1) {
        uint32_t mykey = 0u; bool have = false;
#pragma unroll
        for (int s = 0; s < NSLOT; ++s) {
          const bool valid = ((s << 6) + lane) < C;
          const bool hit = valid && ((kk[s] >> bit) == (prefix >> bit));
          mykey = hit ? kk[s] : mykey;
          have |= hit;
        }
        const uint64_t mb = __ballot(have);
        const int src = __ffsll((unsigned long long)mb) - 1;
        prefix = __shfl(mykey, src);
        k = 1;
        break;
      }
    }
    r = k;
  }

  // ballot-ranked emission, ascending index order
  int sel_run = 0, eq_run = 0;
#pragma unroll
  for (int s = 0; s < NSLOT; ++s) {
    const bool gt = kk[s] > prefix;
    const bool eq = kk[s] == prefix;
    const uint64_t meq = __ballot(eq);
    const int eqrank = eq_run + __popcll(meq & below);
    const bool sel = gt || (eq && (eqrank < r));
    const uint64_t msel = __ballot(sel);
    if (sel) {
      const int pos = sel_run + __popcll(msel & below);
      idx_row[pos] = (float)(int)ki[s];
    }
    sel_run += __popcll(msel);
    eq_run  += __popcll(meq);
  }
}

// ---- kernel 2: selection, 2 waves per row, fast path only ----
__global__ __launch_bounds__(256, 8) void ptk_select(
    const float* __restrict__ x, const float* __restrict__ noise,
    const float* __restrict__ cutf, float* __restrict__ out_idx,
    int* __restrict__ fb_cnt, int* __restrict__ fb_list) {
  // two row-pairs per 256-thread block; per pair: two 256-entry regions
  __shared__ uint2 comp[2][2 * CAP_];
  __shared__ int cnts[2][2];

  const int lane = threadIdx.x & 63;
  const int wave = threadIdx.x >> 6;
  const int pair = wave >> 1;            // 0..1  (row within block)
  const int half = wave & 1;             // 0..1  (half of the row)
  const int row  = blockIdx.x * 2 + pair;  // 0..15999
  const int b = row / NS_;

  const float* __restrict__ xr = x + (size_t)b * D_ + half * HALF_;
  const float* __restrict__ nr = noise + (size_t)row * D_ + half * HALF_;
  const int base_l = lane * HPL_;          // within half
  const int base_i = half * HALF_ + base_l;

  float p[HPL_];
#pragma unroll
  for (int j = 0; j < HPL_; j += 4) {
    const float4 nv = *reinterpret_cast<const float4*>(nr + base_l + j);
    const float4 xv = *reinterpret_cast<const float4*>(xr + base_l + j);
    p[j + 0] = fmaf(SIGMA_, nv.x, xv.x);
    p[j + 1] = fmaf(SIGMA_, nv.y, xv.y);
    p[j + 2] = fmaf(SIGMA_, nv.z, xv.z);
    p[j + 3] = fmaf(SIGMA_, nv.w, xv.w);
  }

  const float cf = cutf[b];   // wave-uniform

  uint32_t m = 0;
#pragma unroll
  for (int j = 0; j < HPL_; ++j) m |= (p[j] >= cf) ? (1u << j) : 0u;
  const int cnt = __popc(m);

  // ballot-based exclusive scan of cnt (5 bits, cnt<=16) -> offset, total Cw
  const uint64_t below = (lane == 0) ? 0ull : ((~0ull) >> (64 - lane));
  int offset = 0, Cw = 0;
#pragma unroll
  for (int t = 0; t < 5; ++t) {
    const uint64_t mb = __ballot((cnt >> t) & 1);
    offset += (int)__popcll(mb & below) << t;
    Cw     += (int)__popcll(mb) << t;
  }
  if (lane == 0) cnts[pair][half] = Cw;

  // compact this half's candidates (ascending index) into its region.
  // static unrolled loop: p[] indices compile-time -> stays in VGPRs.
  {
    int q = half * CAP_ + offset;
#pragma unroll
    for (int j = 0; j < HPL_; ++j) {
      if (m & (1u << j)) {
        comp[pair][q] = make_uint2(order_key(p[j]), (uint32_t)(base_i + j));
        ++q;
      }
    }
  }
  __syncthreads();

  if (half) return;   // odd waves retire; even wave finishes the row

  const int C0 = cnts[pair][0];
  const int C1 = cnts[pair][1];
  const int C  = C0 + C1;

  float* __restrict__ idx_row = out_idx + (size_t)row * TOPK_;

  if (C >= TOPK_ && C <= CAP_) {
    const uint2* cp = comp[pair];
    if (C <= 128)       finish_row<2>(cp, C0, C, idx_row, lane, below);
    else if (C <= 192)  finish_row<3>(cp, C0, C, idx_row, lane, below);
    else                finish_row<4>(cp, C0, C, idx_row, lane, below);
  } else {
    // rare (~7sigma): defer to ptk_fb
    if (lane == 0) {
      const int p_ = atomicAdd(fb_cnt, 1);
      fb_list[p_] = row;
    }
  }
}

// ---- kernel 3: exact full-row select for deferred rows (usually none) ----
__global__ __launch_bounds__(64) void ptk_fb(
    const float* __restrict__ x, const float* __restrict__ noise,
    const int* __restrict__ fb_cnt, const int* __restrict__ fb_list,
    float* __restrict__ out_idx) {
  const int lane = threadIdx.x & 63;
  const int cnt = fb_cnt[0];
  for (int i = blockIdx.x; i < cnt; i += (int)gridDim.x) {
    const int row = fb_list[i];
    const int b = row / NS_;
    const float* __restrict__ xr = x + (size_t)b * D_;
    const float* __restrict__ nr = noise + (size_t)row * D_;
    float* __restrict__ idx_row = out_idx + (size_t)row * TOPK_;

    const int bi = lane * PER_LANE_;
    uint32_t keys[PER_LANE_];
#pragma unroll
    for (int j = 0; j < PER_LANE_; ++j)
      keys[j] = order_key(fmaf(SIGMA_, nr[bi + j], xr[bi + j]));

    uint32_t prefix = 0; int k = TOPK_;
#pragma unroll 1
    for (int bit = 31; bit >= 0; --bit) {
      const uint32_t want = (prefix >> bit) | 1u;
      int c = 0;
#pragma unroll
      for (int j = 0; j < PER_LANE_; ++j) c += ((keys[j] >> bit) == want) ? 1 : 0;
#pragma unroll
      for (int off = 32; off >= 1; off >>= 1) c += __shfl_xor(c, off);
      if (c >= k) prefix |= (1u << bit); else k -= c;
    }
    const int r = k;

    int gt = 0, eq = 0;
#pragma unroll
    for (int j = 0; j < PER_LANE_; ++j) {
      gt += (keys[j] > prefix) ? 1 : 0;
      eq += (keys[j] == prefix) ? 1 : 0;
    }
    uint32_t incl2 = (uint32_t)gt | ((uint32_t)eq << 16);
#pragma unroll
    for (int off = 1; off < 64; off <<= 1) {
      uint32_t y = __shfl_up(incl2, (unsigned)off);
      if (lane >= off) incl2 += y;
    }
    const int gt_base = (int)(incl2 & 0xFFFFu) - gt;
    const int eq_base = (int)(incl2 >> 16) - eq;
    int pos = gt_base + min(eq_base, r);
    int eq_seen = eq_base;
#pragma unroll
    for (int j = 0; j < PER_LANE_; ++j) {
      const uint32_t kj = keys[j];
      bool s = false;
      if (kj > prefix) s = true;
      else if (kj == prefix) { s = (eq_seen < r); eq_seen++; }
      if (s) { idx_row[pos] = (float)(bi + j); pos++; }
    }
  }
}

// ---- kernel 4: histograms -> indicators (writes every element; no memset) ----
__global__ __launch_bounds__(256) void ptk_hist(
    const float* __restrict__ out_idx, float* __restrict__ indicators) {
  __shared__ int hist[JCHUNK_][D_];   // 64 KB

  const int tid   = threadIdx.x;
  const int b     = blockIdx.x >> 4;         // 16 chunks per b
  const int chunk = blockIdx.x & 15;
  const int j0    = chunk * JCHUNK_;

  int4* h4 = (int4*)hist;
  for (int t = tid; t < JCHUNK_ * D_ / 4; t += 256)
    h4[t] = make_int4(0, 0, 0, 0);
  __syncthreads();

  const float* __restrict__ src = out_idx + (size_t)b * NS_ * TOPK_ + j0;
  for (int t = tid; t < NS_ * 2; t += 256) {     // 2 float4 per sample (8 ranks)
    const int n = t >> 1;
    const int q = (t & 1) << 2;
    const float4 v = *reinterpret_cast<const float4*>(src + (size_t)n * TOPK_ + q);
    atomicAdd(&hist[q + 0][(int)v.x], 1);
    atomicAdd(&hist[q + 1][(int)v.y], 1);
    atomicAdd(&hist[q + 2][(int)v.z], 1);
    atomicAdd(&hist[q + 3][(int)v.w], 1);
  }
  __syncthreads();

  float4* __restrict__ dst =
      (float4*)(indicators + ((size_t)b * TOPK_ + j0) * D_);
  for (int t = tid; t < JCHUNK_ * D_ / 4; t += 256) {
    const int4 h = h4[t];
    float4 o;
    o.x = (float)h.x / (float)NS_;
    o.y = (float)h.y / (float)NS_;
    o.z = (float)h.z / (float)NS_;
    o.w = (float)h.w / (float)NS_;
    dst[t] = o;
  }
}

extern "C" void kernel_launch(void* const* d_in, const int* in_sizes, int n_in,
                              void* d_out, int out_size, void* d_ws, size_t ws_size,
                              hipStream_t stream) {
  const float* x     = (const float*)d_in[0];
  const float* noise = (const float*)d_in[1];
  float* indicators  = (float*)d_out;
  float* out_idx     = (float*)d_out + (size_t)B_ * TOPK_ * D_;
  float* cutf        = (float*)d_ws;
  int*   fb_cnt      = (int*)d_ws + 64;    // byte offset 256
  int*   fb_list     = (int*)d_ws + 128;   // up to 16000 ints

  hipLaunchKernelGGL(ptk_cutoff, dim3(B_), dim3(64), 0, stream, x, cutf, fb_cnt);

  const int rows = B_ * NS_;                        // 16000
  hipLaunchKernelGGL(ptk_select, dim3(rows / 2), dim3(256), 0, stream,
                     x, noise, cutf, out_idx, fb_cnt, fb_list);

  hipLaunchKernelGGL(ptk_fb, dim3(64), dim3(64), 0, stream,
                     x, noise, fb_cnt, fb_list, out_idx);

  hipLaunchKernelGGL(ptk_hist, dim3(B_ * 16), dim3(256), 0, stream,
                     out_idx, indicators);
}

// Round 2
// 220.466 us; speedup vs baseline: 1.0176x; 1.0176x over previous
//
#include <hip/hip_runtime.h>

// PerturbedTopK: x(32,2048) f32, noise(32,500,2048) f32.
// out = [indicators (32,128,2048) f32, idx (32,500,128) as f32], concatenated.
//
// R10: launch-count round. R9 (select occupancy fix) was a measured no-op:
// select is near its memory/VALU floor (~25-35us) and the profile is
// dominated by fixed harness fills (~150us) + dispatch gaps. Remaining
// controllable cost is structural: kernels 4 -> 3 by folding the exact
// fallback INTO ptk_select. The two waves of a row-pair already hold the
// full 2048-element row in registers; on the (~7sigma, block-uniform) bad-C
// branch they dump order-keys into LDS (aliased over the candidate buffer,
// 16KB/block, still 8 blocks/CU) and the even wave runs a register-light
// LDS radix + ranked emission. Common path: no extra barrier, no extra VALU.
// fb_cnt/fb_list workspace plumbing removed.

constexpr int B_     = 32;
constexpr int D_     = 2048;
constexpr int NS_    = 500;
constexpr int TOPK_  = 128;
constexpr int SLACK_ = 32;               // cutoff rank = 160
constexpr float SIGMA_  = 0.05f;
constexpr int PER_LANE_ = D_ / 64;       // 32 (cutoff)
constexpr int HALF_  = D_ / 2;           // 1024
constexpr int HPL_   = HALF_ / 64;       // 16 elements per lane per half-row
constexpr int CAP_   = 256;              // fast-path candidate cap (4 slots)
constexpr int JCHUNK_ = 8;               // ranks per hist block
constexpr int CUTBIT_END_ = 14;          // cutoff radix stops here (18 bits)

__device__ __forceinline__ uint32_t order_key(float f) {
  uint32_t u = __float_as_uint(f);
  return (u & 0x80000000u) ? ~u : (u | 0x80000000u);
}
__device__ __forceinline__ float inv_key(uint32_t k) {
  uint32_t u = (k & 0x80000000u) ? (k & 0x7FFFFFFFu) : ~k;
  return __uint_as_float(u);
}

// ---- kernel 1: per-b cutoff ~ (TOPK_+SLACK_)th largest of x_b (18-bit) ----
__global__ __launch_bounds__(64) void ptk_cutoff(const float* __restrict__ x,
                                                 float* __restrict__ cutf) {
  const int lane = threadIdx.x & 63;
  const int b = blockIdx.x;
  const float* __restrict__ xr = x + (size_t)b * D_;
  uint32_t keys[PER_LANE_];
#pragma unroll
  for (int j = 0; j < PER_LANE_; j += 4) {
    const float4 xv = *reinterpret_cast<const float4*>(xr + lane * PER_LANE_ + j);
    keys[j + 0] = order_key(xv.x); keys[j + 1] = order_key(xv.y);
    keys[j + 2] = order_key(xv.z); keys[j + 3] = order_key(xv.w);
  }
  uint32_t prefix = 0; int k = TOPK_ + SLACK_;
#pragma unroll 1
  for (int bit = 31; bit >= CUTBIT_END_; --bit) {
    const uint32_t want = (prefix >> bit) | 1u;
    int c = 0;
#pragma unroll
    for (int j = 0; j < PER_LANE_; ++j) c += ((keys[j] >> bit) == want) ? 1 : 0;
#pragma unroll
    for (int off = 32; off >= 1; off >>= 1) c += __shfl_xor(c, off);
    if (c >= k) prefix |= (1u << bit); else k -= c;
  }
  // prefix has zeros below CUTBIT_END_: floor of the rank-160 key's 18-bit
  // class -> count(x >= cf) >= 160, plus O(1) same-class ties (slack 96).
  if (lane == 0) cutf[b] = inv_key(prefix);
}

// ---- radix select + emission over NSLOT compacted 64-lane slots ----
template <int NSLOT>
__device__ __forceinline__ void finish_row(const uint2* __restrict__ comp,
                                           const int C0, const int C,
                                           float* __restrict__ idx_row,
                                           const int lane, const uint64_t below) {
  uint32_t kk[NSLOT], ki[NSLOT];
#pragma unroll
  for (int s = 0; s < NSLOT; ++s) {
    const int q = (s << 6) + lane;
    const int a = (q < C0) ? q : (CAP_ + q - C0);
    const uint2 v = (q < C) ? comp[a] : make_uint2(0u, 0u);
    kk[s] = v.x; ki[s] = v.y;   // pad key 0 never matches a radix class
  }

  // common-prefix skip: and/or reduce over candidate keys
  uint32_t orv = 0u, andv = 0xFFFFFFFFu;
#pragma unroll
  for (int s = 0; s < NSLOT; ++s) {
    const bool valid = ((s << 6) + lane) < C;
    orv  |= valid ? kk[s] : 0u;
    andv &= valid ? kk[s] : 0xFFFFFFFFu;
  }
#pragma unroll
  for (int off = 32; off >= 1; off >>= 1) {
    orv  |= __shfl_xor(orv, off);
    andv &= __shfl_xor(andv, off);
  }
  const uint32_t diff = orv ^ andv;

  uint32_t prefix; int r;
  if (diff == 0u) {
    prefix = orv; r = TOPK_;
  } else {
    const int startbit = 31 - __clz(diff);
    prefix = (startbit == 31) ? 0u : (andv & (0xFFFFFFFFu << (startbit + 1)));
    int k = TOPK_;
    int A = C;
#pragma unroll 1
    for (int bit = startbit; bit >= 0; --bit) {
      const uint32_t want = (prefix >> bit) | 1u;
      int c = 0;
#pragma unroll
      for (int s = 0; s < NSLOT; ++s)
        c += __popcll(__ballot((kk[s] >> bit) == want));
      if (c >= k) { prefix |= (1u << bit); A = c; }
      else        { k -= c; A -= c; }
      if (A == 1) {
        uint32_t mykey = 0u; bool have = false;
#pragma unroll
        for (int s = 0; s < NSLOT; ++s) {
          const bool valid = ((s << 6) + lane) < C;
          const bool hit = valid && ((kk[s] >> bit) == (prefix >> bit));
          mykey = hit ? kk[s] : mykey;
          have |= hit;
        }
        const uint64_t mb = __ballot(have);
        const int src = __ffsll((unsigned long long)mb) - 1;
        prefix = __shfl(mykey, src);
        k = 1;
        break;
      }
    }
    r = k;
  }

  // ballot-ranked emission, ascending index order
  int sel_run = 0, eq_run = 0;
#pragma unroll
  for (int s = 0; s < NSLOT; ++s) {
    const bool gt = kk[s] > prefix;
    const bool eq = kk[s] == prefix;
    const uint64_t meq = __ballot(eq);
    const int eqrank = eq_run + __popcll(meq & below);
    const bool sel = gt || (eq && (eqrank < r));
    const uint64_t msel = __ballot(sel);
    if (sel) {
      const int pos = sel_run + __popcll(msel & below);
      idx_row[pos] = (float)(int)ki[s];
    }
    sel_run += __popcll(msel);
    eq_run  += __popcll(meq);
  }
}

// ---- kernel 2: selection, 2 waves per row, inline rare fallback ----
__global__ __launch_bounds__(256, 8) void ptk_select(
    const float* __restrict__ x, const float* __restrict__ noise,
    const float* __restrict__ cutf, float* __restrict__ out_idx) {
  // per pair: 8KB region. Fast path uses first 4KB as uint2 comp[512]
  // (two 256-entry half-regions). Rare fallback reuses all 8KB as the
  // row's 2048 order-keys in index order.
  __shared__ uint32_t smem[2][2048];
  __shared__ int cnts[2][2];

  const int lane = threadIdx.x & 63;
  const int wave = threadIdx.x >> 6;
  const int pair = wave >> 1;            // 0..1  (row within block)
  const int half = wave & 1;             // 0..1  (half of the row)
  const int row  = blockIdx.x * 2 + pair;  // 0..15999
  const int b = row / NS_;

  const float* __restrict__ xr = x + (size_t)b * D_ + half * HALF_;
  const float* __restrict__ nr = noise + (size_t)row * D_ + half * HALF_;
  const int base_l = lane * HPL_;          // within half
  const int base_i = half * HALF_ + base_l;

  float p[HPL_];
#pragma unroll
  for (int j = 0; j < HPL_; j += 4) {
    const float4 nv = *reinterpret_cast<const float4*>(nr + base_l + j);
    const float4 xv = *reinterpret_cast<const float4*>(xr + base_l + j);
    p[j + 0] = fmaf(SIGMA_, nv.x, xv.x);
    p[j + 1] = fmaf(SIGMA_, nv.y, xv.y);
    p[j + 2] = fmaf(SIGMA_, nv.z, xv.z);
    p[j + 3] = fmaf(SIGMA_, nv.w, xv.w);
  }

  const float cf = cutf[b];   // wave-uniform

  uint32_t m = 0;
#pragma unroll
  for (int j = 0; j < HPL_; ++j) m |= (p[j] >= cf) ? (1u << j) : 0u;
  const int cnt = __popc(m);

  // ballot-based exclusive scan of cnt (5 bits, cnt<=16) -> offset, total Cw
  const uint64_t below = (lane == 0) ? 0ull : ((~0ull) >> (64 - lane));
  int offset = 0, Cw = 0;
#pragma unroll
  for (int t = 0; t < 5; ++t) {
    const uint64_t mb = __ballot((cnt >> t) & 1);
    offset += (int)__popcll(mb & below) << t;
    Cw     += (int)__popcll(mb) << t;
  }
  if (lane == 0) cnts[pair][half] = Cw;

  uint2* __restrict__ comp = reinterpret_cast<uint2*>(&smem[pair][0]);

  // compact this half's candidates (ascending index) into its region.
  // static unrolled loop: p[] indices compile-time -> stays in VGPRs.
  {
    int q = half * CAP_ + offset;
#pragma unroll
    for (int j = 0; j < HPL_; ++j) {
      if (m & (1u << j)) {
        comp[q] = make_uint2(order_key(p[j]), (uint32_t)(base_i + j));
        ++q;
      }
    }
  }
  __syncthreads();

  const int C0 = cnts[pair][0];
  const int C1 = cnts[pair][1];
  const int C  = C0 + C1;
  // block-uniform fallback decision (so barriers below stay uniform)
  const int Ca = cnts[0][0] + cnts[0][1];
  const int Cb = cnts[1][0] + cnts[1][1];
  const bool anyBad = (Ca < TOPK_) || (Ca > CAP_) || (Cb < TOPK_) || (Cb > CAP_);

  float* __restrict__ idx_row = out_idx + (size_t)row * TOPK_;

  if (!anyBad) {
    if (half) return;   // odd waves retire; even wave finishes the row
    if (C <= 128)       finish_row<2>(comp, C0, C, idx_row, lane, below);
    else if (C <= 192)  finish_row<3>(comp, C0, C, idx_row, lane, below);
    else                finish_row<4>(comp, C0, C, idx_row, lane, below);
    return;
  }

  // ---------- rare (~7sigma) block-uniform fallback ----------
  const bool myBad = (C < TOPK_) || (C > CAP_);
  if (myBad) {
    // dump this wave's keys into smem[pair] in index order (16B stores)
    uint32_t* __restrict__ dst = &smem[pair][half * HALF_ + base_l];
#pragma unroll
    for (int j = 0; j < HPL_; j += 4) {
      uint4 v;
      v.x = order_key(p[j + 0]); v.y = order_key(p[j + 1]);
      v.z = order_key(p[j + 2]); v.w = order_key(p[j + 3]);
      *reinterpret_cast<uint4*>(dst + j) = v;
    }
  }
  __syncthreads();   // all 4 waves (uniform)

  if (half) return;
  if (myBad) {
    // exact 32-bit radix over the 2048 LDS keys (register-light)
    const uint32_t* __restrict__ keys = &smem[pair][0];
    uint32_t prefix = 0; int k = TOPK_;
#pragma unroll 1
    for (int bit = 31; bit >= 0; --bit) {
      const uint32_t want = (prefix >> bit) | 1u;
      int c = 0;
#pragma unroll 1
      for (int t = 0; t < D_; t += 64)
        c += (int)__popcll(__ballot((keys[t + lane] >> bit) == want));
      if (c >= k) prefix |= (1u << bit); else k -= c;
    }
    const int r = k;

    // ranked emission in ascending index order
    int sel_run = 0, eq_run = 0;
#pragma unroll 1
    for (int t = 0; t < D_; t += 64) {
      const uint32_t kj = keys[t + lane];
      const bool gt = kj > prefix;
      const bool eq = kj == prefix;
      const uint64_t meq = __ballot(eq);
      const int eqrank = eq_run + __popcll(meq & below);
      const bool sel = gt || (eq && (eqrank < r));
      const uint64_t msel = __ballot(sel);
      if (sel) idx_row[sel_run + __popcll(msel & below)] = (float)(t + lane);
      sel_run += __popcll(msel);
      eq_run  += __popcll(meq);
    }
  } else {
    // my pair is fine; comp region untouched by the other pair's dump
    if (C <= 128)       finish_row<2>(comp, C0, C, idx_row, lane, below);
    else if (C <= 192)  finish_row<3>(comp, C0, C, idx_row, lane, below);
    else                finish_row<4>(comp, C0, C, idx_row, lane, below);
  }
}

// ---- kernel 3: histograms -> indicators (writes every element; no memset) ----
__global__ __launch_bounds__(256) void ptk_hist(
    const float* __restrict__ out_idx, float* __restrict__ indicators) {
  __shared__ int hist[JCHUNK_][D_];   // 64 KB

  const int tid   = threadIdx.x;
  const int b     = blockIdx.x >> 4;         // 16 chunks per b
  const int chunk = blockIdx.x & 15;
  const int j0    = chunk * JCHUNK_;

  int4* h4 = (int4*)hist;
  for (int t = tid; t < JCHUNK_ * D_ / 4; t += 256)
    h4[t] = make_int4(0, 0, 0, 0);
  __syncthreads();

  const float* __restrict__ src = out_idx + (size_t)b * NS_ * TOPK_ + j0;
  for (int t = tid; t < NS_ * 2; t += 256) {     // 2 float4 per sample (8 ranks)
    const int n = t >> 1;
    const int q = (t & 1) << 2;
    const float4 v = *reinterpret_cast<const float4*>(src + (size_t)n * TOPK_ + q);
    atomicAdd(&hist[q + 0][(int)v.x], 1);
    atomicAdd(&hist[q + 1][(int)v.y], 1);
    atomicAdd(&hist[q + 2][(int)v.z], 1);
    atomicAdd(&hist[q + 3][(int)v.w], 1);
  }
  __syncthreads();

  float4* __restrict__ dst =
      (float4*)(indicators + ((size_t)b * TOPK_ + j0) * D_);
  for (int t = tid; t < JCHUNK_ * D_ / 4; t += 256) {
    const int4 h = h4[t];
    float4 o;
    o.x = (float)h.x / (float)NS_;
    o.y = (float)h.y / (float)NS_;
    o.z = (float)h.z / (float)NS_;
    o.w = (float)h.w / (float)NS_;
    dst[t] = o;
  }
}

extern "C" void kernel_launch(void* const* d_in, const int* in_sizes, int n_in,
                              void* d_out, int out_size, void* d_ws, size_t ws_size,
                              hipStream_t stream) {
  const float* x     = (const float*)d_in[0];
  const float* noise = (const float*)d_in[1];
  float* indicators  = (float*)d_out;
  float* out_idx     = (float*)d_out + (size_t)B_ * TOPK_ * D_;
  float* cutf        = (float*)d_ws;

  hipLaunchKernelGGL(ptk_cutoff, dim3(B_), dim3(64), 0, stream, x, cutf);

  const int rows = B_ * NS_;                        // 16000
  hipLaunchKernelGGL(ptk_select, dim3(rows / 2), dim3(256), 0, stream,
                     x, noise, cutf, out_idx);

  hipLaunchKernelGGL(ptk_hist, dim3(B_ * 16), dim3(256), 0, stream,
                     out_idx, indicators);
}

// Round 3
// 218.735 us; speedup vs baseline: 1.0256x; 1.0079x over previous
//
#include <hip/hip_runtime.h>

// PerturbedTopK: x(32,2048) f32, noise(32,500,2048) f32.
// out = [indicators (32,128,2048) f32, idx (32,500,128) as f32], concatenated.
//
// R11: hist occupancy round. R10 (-4us, matched prediction) leaves ~45us of
// kernel time on ~175us fixed harness fill. Select is at its noise-read BW
// floor (~21-25us; per-SIMD mem 12800cy > VALU 4800cy). Remaining slack:
// ptk_hist ran 256 threads + 64KB LDS -> 2 blocks/CU -> 2 waves/SIMD,
// latency-limited on its 33.5MB store stream. Now 1024 threads/block
// (16 waves x 2 blocks/CU = 8 waves/SIMD, HW max), same grid, same LDS,
// same algorithm; per-thread work quarters. Select/cutoff unchanged.

constexpr int B_     = 32;
constexpr int D_     = 2048;
constexpr int NS_    = 500;
constexpr int TOPK_  = 128;
constexpr int SLACK_ = 32;               // cutoff rank = 160
constexpr float SIGMA_  = 0.05f;
constexpr int PER_LANE_ = D_ / 64;       // 32 (cutoff)
constexpr int HALF_  = D_ / 2;           // 1024
constexpr int HPL_   = HALF_ / 64;       // 16 elements per lane per half-row
constexpr int CAP_   = 256;              // fast-path candidate cap (4 slots)
constexpr int JCHUNK_ = 8;               // ranks per hist block
constexpr int HT_    = 1024;             // hist threads per block
constexpr int CUTBIT_END_ = 14;          // cutoff radix stops here (18 bits)

__device__ __forceinline__ uint32_t order_key(float f) {
  uint32_t u = __float_as_uint(f);
  return (u & 0x80000000u) ? ~u : (u | 0x80000000u);
}
__device__ __forceinline__ float inv_key(uint32_t k) {
  uint32_t u = (k & 0x80000000u) ? (k & 0x7FFFFFFFu) : ~k;
  return __uint_as_float(u);
}

// ---- kernel 1: per-b cutoff ~ (TOPK_+SLACK_)th largest of x_b (18-bit) ----
__global__ __launch_bounds__(64) void ptk_cutoff(const float* __restrict__ x,
                                                 float* __restrict__ cutf) {
  const int lane = threadIdx.x & 63;
  const int b = blockIdx.x;
  const float* __restrict__ xr = x + (size_t)b * D_;
  uint32_t keys[PER_LANE_];
#pragma unroll
  for (int j = 0; j < PER_LANE_; j += 4) {
    const float4 xv = *reinterpret_cast<const float4*>(xr + lane * PER_LANE_ + j);
    keys[j + 0] = order_key(xv.x); keys[j + 1] = order_key(xv.y);
    keys[j + 2] = order_key(xv.z); keys[j + 3] = order_key(xv.w);
  }
  uint32_t prefix = 0; int k = TOPK_ + SLACK_;
#pragma unroll 1
  for (int bit = 31; bit >= CUTBIT_END_; --bit) {
    const uint32_t want = (prefix >> bit) | 1u;
    int c = 0;
#pragma unroll
    for (int j = 0; j < PER_LANE_; ++j) c += ((keys[j] >> bit) == want) ? 1 : 0;
#pragma unroll
    for (int off = 32; off >= 1; off >>= 1) c += __shfl_xor(c, off);
    if (c >= k) prefix |= (1u << bit); else k -= c;
  }
  // prefix has zeros below CUTBIT_END_: floor of the rank-160 key's 18-bit
  // class -> count(x >= cf) >= 160, plus O(1) same-class ties (slack 96).
  if (lane == 0) cutf[b] = inv_key(prefix);
}

// ---- radix select + emission over NSLOT compacted 64-lane slots ----
template <int NSLOT>
__device__ __forceinline__ void finish_row(const uint2* __restrict__ comp,
                                           const int C0, const int C,
                                           float* __restrict__ idx_row,
                                           const int lane, const uint64_t below) {
  uint32_t kk[NSLOT], ki[NSLOT];
#pragma unroll
  for (int s = 0; s < NSLOT; ++s) {
    const int q = (s << 6) + lane;
    const int a = (q < C0) ? q : (CAP_ + q - C0);
    const uint2 v = (q < C) ? comp[a] : make_uint2(0u, 0u);
    kk[s] = v.x; ki[s] = v.y;   // pad key 0 never matches a radix class
  }

  // common-prefix skip: and/or reduce over candidate keys
  uint32_t orv = 0u, andv = 0xFFFFFFFFu;
#pragma unroll
  for (int s = 0; s < NSLOT; ++s) {
    const bool valid = ((s << 6) + lane) < C;
    orv  |= valid ? kk[s] : 0u;
    andv &= valid ? kk[s] : 0xFFFFFFFFu;
  }
#pragma unroll
  for (int off = 32; off >= 1; off >>= 1) {
    orv  |= __shfl_xor(orv, off);
    andv &= __shfl_xor(andv, off);
  }
  const uint32_t diff = orv ^ andv;

  uint32_t prefix; int r;
  if (diff == 0u) {
    prefix = orv; r = TOPK_;
  } else {
    const int startbit = 31 - __clz(diff);
    prefix = (startbit == 31) ? 0u : (andv & (0xFFFFFFFFu << (startbit + 1)));
    int k = TOPK_;
    int A = C;
#pragma unroll 1
    for (int bit = startbit; bit >= 0; --bit) {
      const uint32_t want = (prefix >> bit) | 1u;
      int c = 0;
#pragma unroll
      for (int s = 0; s < NSLOT; ++s)
        c += __popcll(__ballot((kk[s] >> bit) == want));
      if (c >= k) { prefix |= (1u << bit); A = c; }
      else        { k -= c; A -= c; }
      if (A == 1) {
        uint32_t mykey = 0u; bool have = false;
#pragma unroll
        for (int s = 0; s < NSLOT; ++s) {
          const bool valid = ((s << 6) + lane) < C;
          const bool hit = valid && ((kk[s] >> bit) == (prefix >> bit));
          mykey = hit ? kk[s] : mykey;
          have |= hit;
        }
        const uint64_t mb = __ballot(have);
        const int src = __ffsll((unsigned long long)mb) - 1;
        prefix = __shfl(mykey, src);
        k = 1;
        break;
      }
    }
    r = k;
  }

  // ballot-ranked emission, ascending index order
  int sel_run = 0, eq_run = 0;
#pragma unroll
  for (int s = 0; s < NSLOT; ++s) {
    const bool gt = kk[s] > prefix;
    const bool eq = kk[s] == prefix;
    const uint64_t meq = __ballot(eq);
    const int eqrank = eq_run + __popcll(meq & below);
    const bool sel = gt || (eq && (eqrank < r));
    const uint64_t msel = __ballot(sel);
    if (sel) {
      const int pos = sel_run + __popcll(msel & below);
      idx_row[pos] = (float)(int)ki[s];
    }
    sel_run += __popcll(msel);
    eq_run  += __popcll(meq);
  }
}

// ---- kernel 2: selection, 2 waves per row, inline rare fallback ----
__global__ __launch_bounds__(256, 8) void ptk_select(
    const float* __restrict__ x, const float* __restrict__ noise,
    const float* __restrict__ cutf, float* __restrict__ out_idx) {
  // per pair: 8KB region. Fast path uses first 4KB as uint2 comp[512]
  // (two 256-entry half-regions). Rare fallback reuses all 8KB as the
  // row's 2048 order-keys in index order.
  __shared__ uint32_t smem[2][2048];
  __shared__ int cnts[2][2];

  const int lane = threadIdx.x & 63;
  const int wave = threadIdx.x >> 6;
  const int pair = wave >> 1;            // 0..1  (row within block)
  const int half = wave & 1;             // 0..1  (half of the row)
  const int row  = blockIdx.x * 2 + pair;  // 0..15999
  const int b = row / NS_;

  const float* __restrict__ xr = x + (size_t)b * D_ + half * HALF_;
  const float* __restrict__ nr = noise + (size_t)row * D_ + half * HALF_;
  const int base_l = lane * HPL_;          // within half
  const int base_i = half * HALF_ + base_l;

  float p[HPL_];
#pragma unroll
  for (int j = 0; j < HPL_; j += 4) {
    const float4 nv = *reinterpret_cast<const float4*>(nr + base_l + j);
    const float4 xv = *reinterpret_cast<const float4*>(xr + base_l + j);
    p[j + 0] = fmaf(SIGMA_, nv.x, xv.x);
    p[j + 1] = fmaf(SIGMA_, nv.y, xv.y);
    p[j + 2] = fmaf(SIGMA_, nv.z, xv.z);
    p[j + 3] = fmaf(SIGMA_, nv.w, xv.w);
  }

  const float cf = cutf[b];   // wave-uniform

  uint32_t m = 0;
#pragma unroll
  for (int j = 0; j < HPL_; ++j) m |= (p[j] >= cf) ? (1u << j) : 0u;
  const int cnt = __popc(m);

  // ballot-based exclusive scan of cnt (5 bits, cnt<=16) -> offset, total Cw
  const uint64_t below = (lane == 0) ? 0ull : ((~0ull) >> (64 - lane));
  int offset = 0, Cw = 0;
#pragma unroll
  for (int t = 0; t < 5; ++t) {
    const uint64_t mb = __ballot((cnt >> t) & 1);
    offset += (int)__popcll(mb & below) << t;
    Cw     += (int)__popcll(mb) << t;
  }
  if (lane == 0) cnts[pair][half] = Cw;

  uint2* __restrict__ comp = reinterpret_cast<uint2*>(&smem[pair][0]);

  // compact this half's candidates (ascending index) into its region.
  // static unrolled loop: p[] indices compile-time -> stays in VGPRs.
  {
    int q = half * CAP_ + offset;
#pragma unroll
    for (int j = 0; j < HPL_; ++j) {
      if (m & (1u << j)) {
        comp[q] = make_uint2(order_key(p[j]), (uint32_t)(base_i + j));
        ++q;
      }
    }
  }
  __syncthreads();

  const int C0 = cnts[pair][0];
  const int C1 = cnts[pair][1];
  const int C  = C0 + C1;
  // block-uniform fallback decision (so barriers below stay uniform)
  const int Ca = cnts[0][0] + cnts[0][1];
  const int Cb = cnts[1][0] + cnts[1][1];
  const bool anyBad = (Ca < TOPK_) || (Ca > CAP_) || (Cb < TOPK_) || (Cb > CAP_);

  float* __restrict__ idx_row = out_idx + (size_t)row * TOPK_;

  if (!anyBad) {
    if (half) return;   // odd waves retire; even wave finishes the row
    if (C <= 128)       finish_row<2>(comp, C0, C, idx_row, lane, below);
    else if (C <= 192)  finish_row<3>(comp, C0, C, idx_row, lane, below);
    else                finish_row<4>(comp, C0, C, idx_row, lane, below);
    return;
  }

  // ---------- rare (~7sigma) block-uniform fallback ----------
  const bool myBad = (C < TOPK_) || (C > CAP_);
  if (myBad) {
    // dump this wave's keys into smem[pair] in index order (16B stores)
    uint32_t* __restrict__ dst = &smem[pair][half * HALF_ + base_l];
#pragma unroll
    for (int j = 0; j < HPL_; j += 4) {
      uint4 v;
      v.x = order_key(p[j + 0]); v.y = order_key(p[j + 1]);
      v.z = order_key(p[j + 2]); v.w = order_key(p[j + 3]);
      *reinterpret_cast<uint4*>(dst + j) = v;
    }
  }
  __syncthreads();   // all 4 waves (uniform)

  if (half) return;
  if (myBad) {
    // exact 32-bit radix over the 2048 LDS keys (register-light)
    const uint32_t* __restrict__ keys = &smem[pair][0];
    uint32_t prefix = 0; int k = TOPK_;
#pragma unroll 1
    for (int bit = 31; bit >= 0; --bit) {
      const uint32_t want = (prefix >> bit) | 1u;
      int c = 0;
#pragma unroll 1
      for (int t = 0; t < D_; t += 64)
        c += (int)__popcll(__ballot((keys[t + lane] >> bit) == want));
      if (c >= k) prefix |= (1u << bit); else k -= c;
    }
    const int r = k;

    // ranked emission in ascending index order
    int sel_run = 0, eq_run = 0;
#pragma unroll 1
    for (int t = 0; t < D_; t += 64) {
      const uint32_t kj = keys[t + lane];
      const bool gt = kj > prefix;
      const bool eq = kj == prefix;
      const uint64_t meq = __ballot(eq);
      const int eqrank = eq_run + __popcll(meq & below);
      const bool sel = gt || (eq && (eqrank < r));
      const uint64_t msel = __ballot(sel);
      if (sel) idx_row[sel_run + __popcll(msel & below)] = (float)(t + lane);
      sel_run += __popcll(msel);
      eq_run  += __popcll(meq);
    }
  } else {
    // my pair is fine; comp region untouched by the other pair's dump
    if (C <= 128)       finish_row<2>(comp, C0, C, idx_row, lane, below);
    else if (C <= 192)  finish_row<3>(comp, C0, C, idx_row, lane, below);
    else                finish_row<4>(comp, C0, C, idx_row, lane, below);
  }
}

// ---- kernel 3: histograms -> indicators (1024 thr: 8 waves/SIMD) ----
__global__ __launch_bounds__(HT_) void ptk_hist(
    const float* __restrict__ out_idx, float* __restrict__ indicators) {
  __shared__ int hist[JCHUNK_][D_];   // 64 KB -> 2 blocks/CU; 16 waves/block

  const int tid   = threadIdx.x;
  const int b     = blockIdx.x >> 4;         // 16 chunks per b
  const int chunk = blockIdx.x & 15;
  const int j0    = chunk * JCHUNK_;

  int4* h4 = (int4*)hist;
  for (int t = tid; t < JCHUNK_ * D_ / 4; t += HT_)
    h4[t] = make_int4(0, 0, 0, 0);
  __syncthreads();

  const float* __restrict__ src = out_idx + (size_t)b * NS_ * TOPK_ + j0;
  for (int t = tid; t < NS_ * 2; t += HT_) {     // 2 float4 per sample (8 ranks)
    const int n = t >> 1;
    const int q = (t & 1) << 2;
    const float4 v = *reinterpret_cast<const float4*>(src + (size_t)n * TOPK_ + q);
    atomicAdd(&hist[q + 0][(int)v.x], 1);
    atomicAdd(&hist[q + 1][(int)v.y], 1);
    atomicAdd(&hist[q + 2][(int)v.z], 1);
    atomicAdd(&hist[q + 3][(int)v.w], 1);
  }
  __syncthreads();

  float4* __restrict__ dst =
      (float4*)(indicators + ((size_t)b * TOPK_ + j0) * D_);
  for (int t = tid; t < JCHUNK_ * D_ / 4; t += HT_) {
    const int4 h = h4[t];
    float4 o;
    o.x = (float)h.x / (float)NS_;
    o.y = (float)h.y / (float)NS_;
    o.z = (float)h.z / (float)NS_;
    o.w = (float)h.w / (float)NS_;
    dst[t] = o;
  }
}

extern "C" void kernel_launch(void* const* d_in, const int* in_sizes, int n_in,
                              void* d_out, int out_size, void* d_ws, size_t ws_size,
                              hipStream_t stream) {
  const float* x     = (const float*)d_in[0];
  const float* noise = (const float*)d_in[1];
  float* indicators  = (float*)d_out;
  float* out_idx     = (float*)d_out + (size_t)B_ * TOPK_ * D_;
  float* cutf        = (float*)d_ws;

  hipLaunchKernelGGL(ptk_cutoff, dim3(B_), dim3(64), 0, stream, x, cutf);

  const int rows = B_ * NS_;                        // 16000
  hipLaunchKernelGGL(ptk_select, dim3(rows / 2), dim3(256), 0, stream,
                     x, noise, cutf, out_idx);

  hipLaunchKernelGGL(ptk_hist, dim3(B_ * 16), dim3(HT_), 0, stream,
                     out_idx, indicators);
}

// Round 4
// 216.920 us; speedup vs baseline: 1.0342x; 1.0084x over previous
//
#include <hip/hip_runtime.h>

// PerturbedTopK: x(32,2048) f32, noise(32,500,2048) f32.
// out = [indicators (32,128,2048) f32, idx (32,500,128) as f32], concatenated.
//
// R12: emission-coalescing round. R11 (-1.8us) brought hist to ~7-8us
// (floor 6.7); select ~23-25us (floor ~22, noise-read BW); cutoff ~3us;
// harness fills ~155-175us fixed. Last mechanism with a clear counter story:
// fast-path idx emission was 128 divergent scalar global stores/row (4
// partially-coalesced bursts) sharing the vmem issue pipe with the
// HBM-bound noise reads. Now: stage the 128 selected indices in a spare
// 512B LDS region (smem[pair][1024..], unused on the fast path; consecutive
// pos -> conflict-free), then one 512B burst of 64 float2 stores per row.
// -64 vmem instr/row, fully coalesced. Everything else unchanged.
// Stop rule: gain <1.5us -> declare roofline.

constexpr int B_     = 32;
constexpr int D_     = 2048;
constexpr int NS_    = 500;
constexpr int TOPK_  = 128;
constexpr int SLACK_ = 32;               // cutoff rank = 160
constexpr float SIGMA_  = 0.05f;
constexpr int PER_LANE_ = D_ / 64;       // 32 (cutoff)
constexpr int HALF_  = D_ / 2;           // 1024
constexpr int HPL_   = HALF_ / 64;       // 16 elements per lane per half-row
constexpr int CAP_   = 256;              // fast-path candidate cap (4 slots)
constexpr int JCHUNK_ = 8;               // ranks per hist block
constexpr int HT_    = 1024;             // hist threads per block
constexpr int CUTBIT_END_ = 14;          // cutoff radix stops here (18 bits)

__device__ __forceinline__ uint32_t order_key(float f) {
  uint32_t u = __float_as_uint(f);
  return (u & 0x80000000u) ? ~u : (u | 0x80000000u);
}
__device__ __forceinline__ float inv_key(uint32_t k) {
  uint32_t u = (k & 0x80000000u) ? (k & 0x7FFFFFFFu) : ~k;
  return __uint_as_float(u);
}

// ---- kernel 1: per-b cutoff ~ (TOPK_+SLACK_)th largest of x_b (18-bit) ----
__global__ __launch_bounds__(64) void ptk_cutoff(const float* __restrict__ x,
                                                 float* __restrict__ cutf) {
  const int lane = threadIdx.x & 63;
  const int b = blockIdx.x;
  const float* __restrict__ xr = x + (size_t)b * D_;
  uint32_t keys[PER_LANE_];
#pragma unroll
  for (int j = 0; j < PER_LANE_; j += 4) {
    const float4 xv = *reinterpret_cast<const float4*>(xr + lane * PER_LANE_ + j);
    keys[j + 0] = order_key(xv.x); keys[j + 1] = order_key(xv.y);
    keys[j + 2] = order_key(xv.z); keys[j + 3] = order_key(xv.w);
  }
  uint32_t prefix = 0; int k = TOPK_ + SLACK_;
#pragma unroll 1
  for (int bit = 31; bit >= CUTBIT_END_; --bit) {
    const uint32_t want = (prefix >> bit) | 1u;
    int c = 0;
#pragma unroll
    for (int j = 0; j < PER_LANE_; ++j) c += ((keys[j] >> bit) == want) ? 1 : 0;
#pragma unroll
    for (int off = 32; off >= 1; off >>= 1) c += __shfl_xor(c, off);
    if (c >= k) prefix |= (1u << bit); else k -= c;
  }
  // prefix has zeros below CUTBIT_END_: floor of the rank-160 key's 18-bit
  // class -> count(x >= cf) >= 160, plus O(1) same-class ties (slack 96).
  if (lane == 0) cutf[b] = inv_key(prefix);
}

// ---- radix select + emission over NSLOT compacted 64-lane slots ----
// stage: 128-float LDS scratch (consecutive-pos writes -> conflict-free);
// final writeback is one 512B burst of 64 float2 stores.
template <int NSLOT>
__device__ __forceinline__ void finish_row(const uint2* __restrict__ comp,
                                           float* __restrict__ stage,
                                           const int C0, const int C,
                                           float* __restrict__ idx_row,
                                           const int lane, const uint64_t below) {
  uint32_t kk[NSLOT], ki[NSLOT];
#pragma unroll
  for (int s = 0; s < NSLOT; ++s) {
    const int q = (s << 6) + lane;
    const int a = (q < C0) ? q : (CAP_ + q - C0);
    const uint2 v = (q < C) ? comp[a] : make_uint2(0u, 0u);
    kk[s] = v.x; ki[s] = v.y;   // pad key 0 never matches a radix class
  }

  // common-prefix skip: and/or reduce over candidate keys
  uint32_t orv = 0u, andv = 0xFFFFFFFFu;
#pragma unroll
  for (int s = 0; s < NSLOT; ++s) {
    const bool valid = ((s << 6) + lane) < C;
    orv  |= valid ? kk[s] : 0u;
    andv &= valid ? kk[s] : 0xFFFFFFFFu;
  }
#pragma unroll
  for (int off = 32; off >= 1; off >>= 1) {
    orv  |= __shfl_xor(orv, off);
    andv &= __shfl_xor(andv, off);
  }
  const uint32_t diff = orv ^ andv;

  uint32_t prefix; int r;
  if (diff == 0u) {
    prefix = orv; r = TOPK_;
  } else {
    const int startbit = 31 - __clz(diff);
    prefix = (startbit == 31) ? 0u : (andv & (0xFFFFFFFFu << (startbit + 1)));
    int k = TOPK_;
    int A = C;
#pragma unroll 1
    for (int bit = startbit; bit >= 0; --bit) {
      const uint32_t want = (prefix >> bit) | 1u;
      int c = 0;
#pragma unroll
      for (int s = 0; s < NSLOT; ++s)
        c += __popcll(__ballot((kk[s] >> bit) == want));
      if (c >= k) { prefix |= (1u << bit); A = c; }
      else        { k -= c; A -= c; }
      if (A == 1) {
        uint32_t mykey = 0u; bool have = false;
#pragma unroll
        for (int s = 0; s < NSLOT; ++s) {
          const bool valid = ((s << 6) + lane) < C;
          const bool hit = valid && ((kk[s] >> bit) == (prefix >> bit));
          mykey = hit ? kk[s] : mykey;
          have |= hit;
        }
        const uint64_t mb = __ballot(have);
        const int src = __ffsll((unsigned long long)mb) - 1;
        prefix = __shfl(mykey, src);
        k = 1;
        break;
      }
    }
    r = k;
  }

  // ballot-ranked emission into LDS stage, ascending index order
  int sel_run = 0, eq_run = 0;
#pragma unroll
  for (int s = 0; s < NSLOT; ++s) {
    const bool gt = kk[s] > prefix;
    const bool eq = kk[s] == prefix;
    const uint64_t meq = __ballot(eq);
    const int eqrank = eq_run + __popcll(meq & below);
    const bool sel = gt || (eq && (eqrank < r));
    const uint64_t msel = __ballot(sel);
    if (sel) {
      const int pos = sel_run + __popcll(msel & below);
      stage[pos] = (float)(int)ki[s];
    }
    sel_run += __popcll(msel);
    eq_run  += __popcll(meq);
  }

  // coalesced writeback: 64 lanes x float2 = 512B burst (same wave, program
  // order guarantees ds_write -> ds_read ordering via compiler lgkmcnt)
  const float2 o = *reinterpret_cast<const float2*>(&stage[lane * 2]);
  *reinterpret_cast<float2*>(&idx_row[lane * 2]) = o;
}

// ---- kernel 2: selection, 2 waves per row, inline rare fallback ----
__global__ __launch_bounds__(256, 8) void ptk_select(
    const float* __restrict__ x, const float* __restrict__ noise,
    const float* __restrict__ cutf, float* __restrict__ out_idx) {
  // per pair: 8KB region. Fast path: first 4KB = uint2 comp[512] (two
  // 256-entry half-regions); smem[pair][1024..1151] = emission stage.
  // Rare fallback reuses all 8KB as the row's 2048 order-keys.
  __shared__ uint32_t smem[2][2048];
  __shared__ int cnts[2][2];

  const int lane = threadIdx.x & 63;
  const int wave = threadIdx.x >> 6;
  const int pair = wave >> 1;            // 0..1  (row within block)
  const int half = wave & 1;             // 0..1  (half of the row)
  const int row  = blockIdx.x * 2 + pair;  // 0..15999
  const int b = row / NS_;

  const float* __restrict__ xr = x + (size_t)b * D_ + half * HALF_;
  const float* __restrict__ nr = noise + (size_t)row * D_ + half * HALF_;
  const int base_l = lane * HPL_;          // within half
  const int base_i = half * HALF_ + base_l;

  float p[HPL_];
#pragma unroll
  for (int j = 0; j < HPL_; j += 4) {
    const float4 nv = *reinterpret_cast<const float4*>(nr + base_l + j);
    const float4 xv = *reinterpret_cast<const float4*>(xr + base_l + j);
    p[j + 0] = fmaf(SIGMA_, nv.x, xv.x);
    p[j + 1] = fmaf(SIGMA_, nv.y, xv.y);
    p[j + 2] = fmaf(SIGMA_, nv.z, xv.z);
    p[j + 3] = fmaf(SIGMA_, nv.w, xv.w);
  }

  const float cf = cutf[b];   // wave-uniform

  uint32_t m = 0;
#pragma unroll
  for (int j = 0; j < HPL_; ++j) m |= (p[j] >= cf) ? (1u << j) : 0u;
  const int cnt = __popc(m);

  // ballot-based exclusive scan of cnt (5 bits, cnt<=16) -> offset, total Cw
  const uint64_t below = (lane == 0) ? 0ull : ((~0ull) >> (64 - lane));
  int offset = 0, Cw = 0;
#pragma unroll
  for (int t = 0; t < 5; ++t) {
    const uint64_t mb = __ballot((cnt >> t) & 1);
    offset += (int)__popcll(mb & below) << t;
    Cw     += (int)__popcll(mb) << t;
  }
  if (lane == 0) cnts[pair][half] = Cw;

  uint2* __restrict__ comp = reinterpret_cast<uint2*>(&smem[pair][0]);

  // compact this half's candidates (ascending index) into its region.
  // static unrolled loop: p[] indices compile-time -> stays in VGPRs.
  {
    int q = half * CAP_ + offset;
#pragma unroll
    for (int j = 0; j < HPL_; ++j) {
      if (m & (1u << j)) {
        comp[q] = make_uint2(order_key(p[j]), (uint32_t)(base_i + j));
        ++q;
      }
    }
  }
  __syncthreads();

  const int C0 = cnts[pair][0];
  const int C1 = cnts[pair][1];
  const int C  = C0 + C1;
  // block-uniform fallback decision (so barriers below stay uniform)
  const int Ca = cnts[0][0] + cnts[0][1];
  const int Cb = cnts[1][0] + cnts[1][1];
  const bool anyBad = (Ca < TOPK_) || (Ca > CAP_) || (Cb < TOPK_) || (Cb > CAP_);

  float* __restrict__ idx_row = out_idx + (size_t)row * TOPK_;
  float* __restrict__ stage = reinterpret_cast<float*>(&smem[pair][1024]);

  if (!anyBad) {
    if (half) return;   // odd waves retire; even wave finishes the row
    if (C <= 128)       finish_row<2>(comp, stage, C0, C, idx_row, lane, below);
    else if (C <= 192)  finish_row<3>(comp, stage, C0, C, idx_row, lane, below);
    else                finish_row<4>(comp, stage, C0, C, idx_row, lane, below);
    return;
  }

  // ---------- rare (~7sigma) block-uniform fallback ----------
  const bool myBad = (C < TOPK_) || (C > CAP_);
  if (myBad) {
    // dump this wave's keys into smem[pair] in index order (16B stores)
    uint32_t* __restrict__ dst = &smem[pair][half * HALF_ + base_l];
#pragma unroll
    for (int j = 0; j < HPL_; j += 4) {
      uint4 v;
      v.x = order_key(p[j + 0]); v.y = order_key(p[j + 1]);
      v.z = order_key(p[j + 2]); v.w = order_key(p[j + 3]);
      *reinterpret_cast<uint4*>(dst + j) = v;
    }
  }
  __syncthreads();   // all 4 waves (uniform)

  if (half) return;
  if (myBad) {
    // exact 32-bit radix over the 2048 LDS keys (register-light)
    const uint32_t* __restrict__ keys = &smem[pair][0];
    uint32_t prefix = 0; int k = TOPK_;
#pragma unroll 1
    for (int bit = 31; bit >= 0; --bit) {
      const uint32_t want = (prefix >> bit) | 1u;
      int c = 0;
#pragma unroll 1
      for (int t = 0; t < D_; t += 64)
        c += (int)__popcll(__ballot((keys[t + lane] >> bit) == want));
      if (c >= k) prefix |= (1u << bit); else k -= c;
    }
    const int r = k;

    // ranked emission in ascending index order
    int sel_run = 0, eq_run = 0;
#pragma unroll 1
    for (int t = 0; t < D_; t += 64) {
      const uint32_t kj = keys[t + lane];
      const bool gt = kj > prefix;
      const bool eq = kj == prefix;
      const uint64_t meq = __ballot(eq);
      const int eqrank = eq_run + __popcll(meq & below);
      const bool sel = gt || (eq && (eqrank < r));
      const uint64_t msel = __ballot(sel);
      if (sel) idx_row[sel_run + __popcll(msel & below)] = (float)(t + lane);
      sel_run += __popcll(msel);
      eq_run  += __popcll(meq);
    }
  } else {
    // my pair is fine; comp region untouched by the other pair's dump
    if (C <= 128)       finish_row<2>(comp, stage, C0, C, idx_row, lane, below);
    else if (C <= 192)  finish_row<3>(comp, stage, C0, C, idx_row, lane, below);
    else                finish_row<4>(comp, stage, C0, C, idx_row, lane, below);
  }
}

// ---- kernel 3: histograms -> indicators (1024 thr: 8 waves/SIMD) ----
__global__ __launch_bounds__(HT_) void ptk_hist(
    const float* __restrict__ out_idx, float* __restrict__ indicators) {
  __shared__ int hist[JCHUNK_][D_];   // 64 KB -> 2 blocks/CU; 16 waves/block

  const int tid   = threadIdx.x;
  const int b     = blockIdx.x >> 4;         // 16 chunks per b
  const int chunk = blockIdx.x & 15;
  const int j0    = chunk * JCHUNK_;

  int4* h4 = (int4*)hist;
  for (int t = tid; t < JCHUNK_ * D_ / 4; t += HT_)
    h4[t] = make_int4(0, 0, 0, 0);
  __syncthreads();

  const float* __restrict__ src = out_idx + (size_t)b * NS_ * TOPK_ + j0;
  for (int t = tid; t < NS_ * 2; t += HT_) {     // 2 float4 per sample (8 ranks)
    const int n = t >> 1;
    const int q = (t & 1) << 2;
    const float4 v = *reinterpret_cast<const float4*>(src + (size_t)n * TOPK_ + q);
    atomicAdd(&hist[q + 0][(int)v.x], 1);
    atomicAdd(&hist[q + 1][(int)v.y], 1);
    atomicAdd(&hist[q + 2][(int)v.z], 1);
    atomicAdd(&hist[q + 3][(int)v.w], 1);
  }
  __syncthreads();

  float4* __restrict__ dst =
      (float4*)(indicators + ((size_t)b * TOPK_ + j0) * D_);
  for (int t = tid; t < JCHUNK_ * D_ / 4; t += HT_) {
    const int4 h = h4[t];
    float4 o;
    o.x = (float)h.x / (float)NS_;
    o.y = (float)h.y / (float)NS_;
    o.z = (float)h.z / (float)NS_;
    o.w = (float)h.w / (float)NS_;
    dst[t] = o;
  }
}

extern "C" void kernel_launch(void* const* d_in, const int* in_sizes, int n_in,
                              void* d_out, int out_size, void* d_ws, size_t ws_size,
                              hipStream_t stream) {
  const float* x     = (const float*)d_in[0];
  const float* noise = (const float*)d_in[1];
  float* indicators  = (float*)d_out;
  float* out_idx     = (float*)d_out + (size_t)B_ * TOPK_ * D_;
  float* cutf        = (float*)d_ws;

  hipLaunchKernelGGL(ptk_cutoff, dim3(B_), dim3(64), 0, stream, x, cutf);

  const int rows = B_ * NS_;                        // 16000
  hipLaunchKernelGGL(ptk_select, dim3(rows / 2), dim3(256), 0, stream,
                     x, noise, cutf, out_idx);

  hipLaunchKernelGGL(ptk_hist, dim3(B_ * 16), dim3(HT_), 0, stream,
                     out_idx, indicators);
}